// Round 1
// baseline (971.707 us; speedup 1.0000x reference)
//
#include <hip/hip_runtime.h>

#define N_TOK 131072
#define D_IN  512
#define GHID  64
#define E_EXP 16
#define CAPE  8192
#define H_DIM 128
#define O_DIM 512

// ---------------- K1: gating (x@Wg1+bg1 relu) @ Wg2 + bg2 -> argmax ----------------
// Block: 256 thr, 64 tokens, full 64 hidden, K=512 in 32-steps.
__global__ __launch_bounds__(256) void gating_kernel(
    const float* __restrict__ x, const float* __restrict__ Wg1,
    const float* __restrict__ bg1, const float* __restrict__ Wg2,
    const float* __restrict__ bg2, int* __restrict__ top_expert)
{
    __shared__ float As[32][65];   // [k][m]
    __shared__ float Bs[32][64];   // [k][n]
    __shared__ float hs[64][65];   // [m][n] hidden
    __shared__ float wg2s[64][16];
    __shared__ float lg[64][17];

    const int tid = threadIdx.x;
    const int m_base = blockIdx.x * 64;
    const int tx = tid & 15, ty = tid >> 4;
    const int m0 = ty * 4, n0 = tx * 4;

    const int lm = tid & 63;        // token for A-load
    const int lk = (tid >> 6) * 8;  // k-offset for A-load

    float acc[4][4] = {};

    for (int kt = 0; kt < 512; kt += 32) {
        // A tile: x[m_base+lm][kt+lk .. +8] -> As[lk+u][lm] (transposed)
        const float4* xp = reinterpret_cast<const float4*>(&x[(size_t)(m_base + lm) * D_IN + kt + lk]);
        float4 a0 = xp[0], a1 = xp[1];
        As[lk+0][lm] = a0.x; As[lk+1][lm] = a0.y; As[lk+2][lm] = a0.z; As[lk+3][lm] = a0.w;
        As[lk+4][lm] = a1.x; As[lk+5][lm] = a1.y; As[lk+6][lm] = a1.z; As[lk+7][lm] = a1.w;
        // B tile: Wg1[(kt+bk)*64 + bn]
        {
            int i  = tid * 8;
            int bk = i >> 6, bn = i & 63;
            const float4* wp = reinterpret_cast<const float4*>(&Wg1[(size_t)(kt + bk) * GHID + bn]);
            float4 b0 = wp[0], b1v = wp[1];
            *reinterpret_cast<float4*>(&Bs[bk][bn])     = b0;
            *reinterpret_cast<float4*>(&Bs[bk][bn + 4]) = b1v;
        }
        __syncthreads();
        #pragma unroll 8
        for (int k = 0; k < 32; ++k) {
            float4 av = *reinterpret_cast<const float4*>(&As[k][m0]);
            float4 bv = *reinterpret_cast<const float4*>(&Bs[k][n0]);
            float a[4] = {av.x, av.y, av.z, av.w};
            float b[4] = {bv.x, bv.y, bv.z, bv.w};
            #pragma unroll
            for (int i = 0; i < 4; ++i)
                #pragma unroll
                for (int j = 0; j < 4; ++j)
                    acc[i][j] += a[i] * b[j];
        }
        __syncthreads();
    }
    // bias + relu -> hs
    #pragma unroll
    for (int i = 0; i < 4; ++i)
        #pragma unroll
        for (int j = 0; j < 4; ++j) {
            float v = acc[i][j] + bg1[n0 + j];
            hs[m0 + i][n0 + j] = v > 0.f ? v : 0.f;
        }
    for (int i = tid; i < 64 * 16; i += 256) wg2s[i >> 4][i & 15] = Wg2[i];
    __syncthreads();
    // logits: 64 tokens x 16 experts; thread -> (m = tid&63, rep = tid>>6 covers 4 experts)
    {
        const int m = tid & 63;
        const int rep = tid >> 6;
        float lacc[4];
        #pragma unroll
        for (int q = 0; q < 4; ++q) lacc[q] = bg2[rep * 4 + q];
        for (int j = 0; j < 64; ++j) {
            float hv = hs[m][j];
            #pragma unroll
            for (int q = 0; q < 4; ++q) lacc[q] += hv * wg2s[j][rep * 4 + q];
        }
        #pragma unroll
        for (int q = 0; q < 4; ++q) lg[m][rep * 4 + q] = lacc[q];
    }
    __syncthreads();
    if (tid < 64) {
        float best = lg[tid][0]; int be = 0;
        #pragma unroll
        for (int e = 1; e < 16; ++e) {
            float v = lg[tid][e];
            if (v > best) { best = v; be = e; }   // strict > : first-occurrence argmax like numpy
        }
        top_expert[m_base + tid] = be;
    }
}

// ---------------- P1: per-512-token-chunk expert histogram ----------------
__global__ __launch_bounds__(256) void count_kernel(const int* __restrict__ te,
                                                    int* __restrict__ blockCounts)
{
    __shared__ int cnt[16];
    if (threadIdx.x < 16) cnt[threadIdx.x] = 0;
    __syncthreads();
    int base = blockIdx.x * 512;
    for (int i = threadIdx.x; i < 512; i += 256)
        atomicAdd(&cnt[te[base + i]], 1);
    __syncthreads();
    if (threadIdx.x < 16) blockCounts[blockIdx.x * 16 + threadIdx.x] = cnt[threadIdx.x];
}

// ---------------- P2: exclusive scan over chunks, per expert ----------------
__global__ void scan_kernel(const int* __restrict__ blockCounts,
                            int* __restrict__ blockOffs, int* __restrict__ totals)
{
    int e = threadIdx.x;
    if (e < 16) {
        int run = 0;
        for (int b = 0; b < 256; ++b) {
            blockOffs[b * 16 + e] = run;
            run += blockCounts[b * 16 + e];
        }
        totals[e] = run;
    }
}

// ---------------- P3: in-order ballot prefix -> slot_token scatter ----------------
__global__ __launch_bounds__(64) void scatter_kernel(const int* __restrict__ te,
        const int* __restrict__ blockOffs, int* __restrict__ slot_token,
        int* __restrict__ dropCount, int* __restrict__ dropList)
{
    const int b = blockIdx.x;
    const int lane = threadIdx.x;
    int running[16];
    #pragma unroll
    for (int e = 0; e < 16; ++e) running[e] = blockOffs[b * 16 + e];
    const unsigned long long lt = (lane == 0) ? 0ull : ((~0ull) >> (64 - lane));
    const int base = b * 512;
    for (int g = 0; g < 8; ++g) {
        int n = base + g * 64 + lane;
        int e = te[n];
        int p = 0;
        #pragma unroll
        for (int ee = 0; ee < 16; ++ee) {
            unsigned long long bal = __ballot(e == ee);
            if (e == ee) p = running[ee] + __popcll(bal & lt);
            running[ee] += __popcll(bal);
        }
        if (p < CAPE) {
            slot_token[e * CAPE + p] = n;
        } else {
            int di = atomicAdd(dropCount, 1);
            dropList[di] = n;
        }
    }
}

// ---------------- K4: per-expert MLP + softmax, writes out[token] directly ----------------
// Block: 256 thr, 16 slots of one expert.
__global__ __launch_bounds__(256) void expert_kernel(
    const float* __restrict__ x, const float* __restrict__ W1, const float* __restrict__ b1,
    const float* __restrict__ W2, const float* __restrict__ b2,
    const int* __restrict__ slot_token, const int* __restrict__ totals,
    float* __restrict__ out)
{
    __shared__ float xs[16][512];
    __shared__ float hsm[16][128];
    __shared__ int   toks[16];

    const int tid = threadIdx.x;
    const int e   = blockIdx.x >> 9;    // /512
    const int sb  = blockIdx.x & 511;
    const int slot0 = sb * 16;
    int vc = totals[e]; if (vc > CAPE) vc = CAPE;
    if (slot0 >= vc) return;
    int nt = vc - slot0; if (nt > 16) nt = 16;

    if (tid < 16) toks[tid] = (tid < nt) ? slot_token[e * CAPE + slot0 + tid] : 0;
    __syncthreads();

    // stage x rows (zeros for invalid slots)
    #pragma unroll
    for (int r = 0; r < 8; ++r) {
        int i = r * 256 + tid;           // float4 index 0..2047
        int t = i >> 7, c = (i & 127) << 2;
        float4 v = make_float4(0.f, 0.f, 0.f, 0.f);
        if (t < nt) v = *reinterpret_cast<const float4*>(&x[(size_t)toks[t] * D_IN + c]);
        *reinterpret_cast<float4*>(&xs[t][c]) = v;
    }
    __syncthreads();

    // phase 1: h = relu(x @ W1[e] + b1[e]); thread = (token ty, 8 hiddens at tx*8)
    {
        const int tx = tid & 15, ty = tid >> 4;
        const int h0 = tx * 8;
        float acc[8];
        #pragma unroll
        for (int i = 0; i < 8; ++i) acc[i] = b1[e * H_DIM + h0 + i];
        const float* w1p = &W1[(size_t)e * D_IN * H_DIM + h0];
        for (int k = 0; k < 512; ++k) {
            float xv = xs[ty][k];
            float4 w0  = *reinterpret_cast<const float4*>(&w1p[(size_t)k * H_DIM]);
            float4 w1v = *reinterpret_cast<const float4*>(&w1p[(size_t)k * H_DIM + 4]);
            acc[0] += xv * w0.x;  acc[1] += xv * w0.y;  acc[2] += xv * w0.z;  acc[3] += xv * w0.w;
            acc[4] += xv * w1v.x; acc[5] += xv * w1v.y; acc[6] += xv * w1v.z; acc[7] += xv * w1v.w;
        }
        #pragma unroll
        for (int i = 0; i < 8; ++i) hsm[ty][h0 + i] = acc[i] > 0.f ? acc[i] : 0.f;
    }
    __syncthreads();

    // phase 2: o = softmax(h @ W2[e] + b2[e]); wave = 4 tokens (ty), lane covers 8 outputs
    {
        const int tx = tid & 63, ty = tid >> 6;
        const int o0 = tx * 8;
        float acc[4][8];
        #pragma unroll
        for (int j = 0; j < 4; ++j)
            #pragma unroll
            for (int i = 0; i < 8; ++i) acc[j][i] = b2[e * O_DIM + o0 + i];
        const float* w2p = &W2[(size_t)e * H_DIM * O_DIM + o0];
        for (int k = 0; k < 128; ++k) {
            float4 w0  = *reinterpret_cast<const float4*>(&w2p[(size_t)k * O_DIM]);
            float4 w1v = *reinterpret_cast<const float4*>(&w2p[(size_t)k * O_DIM + 4]);
            #pragma unroll
            for (int j = 0; j < 4; ++j) {
                float hv = hsm[ty * 4 + j][k];
                acc[j][0] += hv * w0.x;  acc[j][1] += hv * w0.y;  acc[j][2] += hv * w0.z;  acc[j][3] += hv * w0.w;
                acc[j][4] += hv * w1v.x; acc[j][5] += hv * w1v.y; acc[j][6] += hv * w1v.z; acc[j][7] += hv * w1v.w;
            }
        }
        #pragma unroll
        for (int j = 0; j < 4; ++j) {
            int t = ty * 4 + j;
            float m = acc[j][0];
            #pragma unroll
            for (int i = 1; i < 8; ++i) m = fmaxf(m, acc[j][i]);
            #pragma unroll
            for (int s = 1; s < 64; s <<= 1) m = fmaxf(m, __shfl_xor(m, s, 64));
            float ex[8], sum = 0.f;
            #pragma unroll
            for (int i = 0; i < 8; ++i) { ex[i] = expf(acc[j][i] - m); sum += ex[i]; }
            #pragma unroll
            for (int s = 1; s < 64; s <<= 1) sum += __shfl_xor(sum, s, 64);
            float inv = 1.f / sum;
            if (t < nt) {
                float* op = &out[(size_t)toks[t] * O_DIM + o0];
                *reinterpret_cast<float4*>(op)     = make_float4(ex[0]*inv, ex[1]*inv, ex[2]*inv, ex[3]*inv);
                *reinterpret_cast<float4*>(op + 4) = make_float4(ex[4]*inv, ex[5]*inv, ex[6]*inv, ex[7]*inv);
            }
        }
    }
}

// ---------------- K5: zero rows of dropped tokens ----------------
__global__ __launch_bounds__(256) void zero_dropped_kernel(const int* __restrict__ dropCount,
        const int* __restrict__ dropList, float* __restrict__ out)
{
    int cnt = *dropCount;
    for (int i = blockIdx.x; i < cnt; i += gridDim.x) {
        int n = dropList[i];
        reinterpret_cast<float2*>(&out[(size_t)n * O_DIM])[threadIdx.x] = make_float2(0.f, 0.f);
    }
}

extern "C" void kernel_launch(void* const* d_in, const int* in_sizes, int n_in,
                              void* d_out, int out_size, void* d_ws, size_t ws_size,
                              hipStream_t stream) {
    (void)in_sizes; (void)n_in; (void)out_size; (void)ws_size;
    const float* x   = (const float*)d_in[0];
    const float* Wg1 = (const float*)d_in[1];
    const float* bg1 = (const float*)d_in[2];
    const float* Wg2 = (const float*)d_in[3];
    const float* bg2 = (const float*)d_in[4];
    const float* W1  = (const float*)d_in[5];
    const float* b1  = (const float*)d_in[6];
    const float* W2  = (const float*)d_in[7];
    const float* b2  = (const float*)d_in[8];
    float* out = (float*)d_out;

    char* ws = (char*)d_ws;
    int* dropCount   = (int*)(ws);                                   // 4 B (memset)
    int* top_expert  = (int*)(ws + 256);                             // 512 KB
    int* blockCounts = (int*)(ws + 256 + 524288);                    // 16 KB
    int* blockOffs   = (int*)(ws + 256 + 524288 + 16384);            // 16 KB
    int* totals      = (int*)(ws + 256 + 524288 + 32768);            // 64 B
    int* slot_token  = (int*)(ws + 256 + 524288 + 32768 + 256);      // 512 KB
    int* dropList    = (int*)(ws + 256 + 524288 + 32768 + 256 + 524288); // 512 KB

    hipMemsetAsync(dropCount, 0, 4, stream);
    gating_kernel<<<N_TOK / 64, 256, 0, stream>>>(x, Wg1, bg1, Wg2, bg2, top_expert);
    count_kernel<<<N_TOK / 512, 256, 0, stream>>>(top_expert, blockCounts);
    scan_kernel<<<1, 64, 0, stream>>>(blockCounts, blockOffs, totals);
    scatter_kernel<<<N_TOK / 512, 64, 0, stream>>>(top_expert, blockOffs, slot_token, dropCount, dropList);
    expert_kernel<<<E_EXP * (CAPE / 16), 256, 0, stream>>>(x, W1, b1, W2, b2, slot_token, totals, out);
    zero_dropped_kernel<<<256, 256, 0, stream>>>(dropCount, dropList, out);
}

// Round 2
// 459.044 us; speedup vs baseline: 2.1168x; 2.1168x over previous
//
#include <hip/hip_runtime.h>

#define N_TOK 131072
#define D_IN  512
#define GHID  64
#define E_EXP 16
#define CAPE  8192
#define H_DIM 128
#define O_DIM 512

typedef __attribute__((ext_vector_type(8))) short bf16x8;
typedef __attribute__((ext_vector_type(4))) float f32x4;

__device__ __forceinline__ ushort f2bf(float f) {
    uint u = __builtin_bit_cast(uint, f);
    u = u + 0x7FFFu + ((u >> 16) & 1u);   // RNE
    return (ushort)(u >> 16);
}

// ---------------- K1: gating (x@Wg1+bg1 relu) @ Wg2 + bg2 -> argmax (fp32, unchanged) ----------------
__global__ __launch_bounds__(256) void gating_kernel(
    const float* __restrict__ x, const float* __restrict__ Wg1,
    const float* __restrict__ bg1, const float* __restrict__ Wg2,
    const float* __restrict__ bg2, int* __restrict__ top_expert)
{
    __shared__ float As[32][65];
    __shared__ float Bs[32][64];
    __shared__ float hs[64][65];
    __shared__ float wg2s[64][16];
    __shared__ float lg[64][17];

    const int tid = threadIdx.x;
    const int m_base = blockIdx.x * 64;
    const int tx = tid & 15, ty = tid >> 4;
    const int m0 = ty * 4, n0 = tx * 4;

    const int lm = tid & 63;
    const int lk = (tid >> 6) * 8;

    float acc[4][4] = {};

    for (int kt = 0; kt < 512; kt += 32) {
        const float4* xp = reinterpret_cast<const float4*>(&x[(size_t)(m_base + lm) * D_IN + kt + lk]);
        float4 a0 = xp[0], a1 = xp[1];
        As[lk+0][lm] = a0.x; As[lk+1][lm] = a0.y; As[lk+2][lm] = a0.z; As[lk+3][lm] = a0.w;
        As[lk+4][lm] = a1.x; As[lk+5][lm] = a1.y; As[lk+6][lm] = a1.z; As[lk+7][lm] = a1.w;
        {
            int i  = tid * 8;
            int bk = i >> 6, bn = i & 63;
            const float4* wp = reinterpret_cast<const float4*>(&Wg1[(size_t)(kt + bk) * GHID + bn]);
            float4 b0 = wp[0], b1v = wp[1];
            *reinterpret_cast<float4*>(&Bs[bk][bn])     = b0;
            *reinterpret_cast<float4*>(&Bs[bk][bn + 4]) = b1v;
        }
        __syncthreads();
        #pragma unroll 8
        for (int k = 0; k < 32; ++k) {
            float4 av = *reinterpret_cast<const float4*>(&As[k][m0]);
            float4 bv = *reinterpret_cast<const float4*>(&Bs[k][n0]);
            float a[4] = {av.x, av.y, av.z, av.w};
            float b[4] = {bv.x, bv.y, bv.z, bv.w};
            #pragma unroll
            for (int i = 0; i < 4; ++i)
                #pragma unroll
                for (int j = 0; j < 4; ++j)
                    acc[i][j] += a[i] * b[j];
        }
        __syncthreads();
    }
    #pragma unroll
    for (int i = 0; i < 4; ++i)
        #pragma unroll
        for (int j = 0; j < 4; ++j) {
            float v = acc[i][j] + bg1[n0 + j];
            hs[m0 + i][n0 + j] = v > 0.f ? v : 0.f;
        }
    for (int i = tid; i < 64 * 16; i += 256) wg2s[i >> 4][i & 15] = Wg2[i];
    __syncthreads();
    {
        const int m = tid & 63;
        const int rep = tid >> 6;
        float lacc[4];
        #pragma unroll
        for (int q = 0; q < 4; ++q) lacc[q] = bg2[rep * 4 + q];
        for (int j = 0; j < 64; ++j) {
            float hv = hs[m][j];
            #pragma unroll
            for (int q = 0; q < 4; ++q) lacc[q] += hv * wg2s[j][rep * 4 + q];
        }
        #pragma unroll
        for (int q = 0; q < 4; ++q) lg[m][rep * 4 + q] = lacc[q];
    }
    __syncthreads();
    if (tid < 64) {
        float best = lg[tid][0]; int be = 0;
        #pragma unroll
        for (int e = 1; e < 16; ++e) {
            float v = lg[tid][e];
            if (v > best) { best = v; be = e; }
        }
        top_expert[m_base + tid] = be;
    }
}

// ---------------- P1..P3: routing (unchanged) ----------------
__global__ __launch_bounds__(256) void count_kernel(const int* __restrict__ te,
                                                    int* __restrict__ blockCounts)
{
    __shared__ int cnt[16];
    if (threadIdx.x < 16) cnt[threadIdx.x] = 0;
    __syncthreads();
    int base = blockIdx.x * 512;
    for (int i = threadIdx.x; i < 512; i += 256)
        atomicAdd(&cnt[te[base + i]], 1);
    __syncthreads();
    if (threadIdx.x < 16) blockCounts[blockIdx.x * 16 + threadIdx.x] = cnt[threadIdx.x];
}

__global__ void scan_kernel(const int* __restrict__ blockCounts,
                            int* __restrict__ blockOffs, int* __restrict__ totals)
{
    int e = threadIdx.x;
    if (e < 16) {
        int run = 0;
        for (int b = 0; b < 256; ++b) {
            blockOffs[b * 16 + e] = run;
            run += blockCounts[b * 16 + e];
        }
        totals[e] = run;
    }
}

__global__ __launch_bounds__(64) void scatter_kernel(const int* __restrict__ te,
        const int* __restrict__ blockOffs, int* __restrict__ slot_token,
        int* __restrict__ dropCount, int* __restrict__ dropList)
{
    const int b = blockIdx.x;
    const int lane = threadIdx.x;
    int running[16];
    #pragma unroll
    for (int e = 0; e < 16; ++e) running[e] = blockOffs[b * 16 + e];
    const unsigned long long lt = (lane == 0) ? 0ull : ((~0ull) >> (64 - lane));
    const int base = b * 512;
    for (int g = 0; g < 8; ++g) {
        int n = base + g * 64 + lane;
        int e = te[n];
        int p = 0;
        #pragma unroll
        for (int ee = 0; ee < 16; ++ee) {
            unsigned long long bal = __ballot(e == ee);
            if (e == ee) p = running[ee] + __popcll(bal & lt);
            running[ee] += __popcll(bal);
        }
        if (p < CAPE) {
            slot_token[e * CAPE + p] = n;
        } else {
            int di = atomicAdd(dropCount, 1);
            dropList[di] = n;
        }
    }
}

// ---------------- Wc: transpose + fp32->bf16 convert:  in [E][R][C] f32 -> out [E][C][R] bf16 ----------------
template<int R, int C>
__global__ __launch_bounds__(256) void cvt_transpose_kernel(const float* __restrict__ in,
                                                            ushort* __restrict__ out)
{
    __shared__ float s[32][33];
    const int tilesC = C / 32;
    const int tilesR = R / 32;
    int bid = blockIdx.x;
    int e = bid / (tilesR * tilesC);
    int t = bid % (tilesR * tilesC);
    int r0 = (t / tilesC) * 32, c0 = (t % tilesC) * 32;
    const float* ip = in + (size_t)e * R * C;
    ushort* op = out + (size_t)e * C * R;
    int j = threadIdx.x & 31, i0 = threadIdx.x >> 5;
    #pragma unroll
    for (int p = 0; p < 4; ++p) {
        int i = i0 + p * 8;
        s[i][j] = ip[(size_t)(r0 + i) * C + (c0 + j)];
    }
    __syncthreads();
    #pragma unroll
    for (int p = 0; p < 4; ++p) {
        int cc = i0 + p * 8;
        op[(size_t)(c0 + cc) * R + (r0 + j)] = f2bf(s[j][cc]);
    }
}

// ---------------- K4: per-expert MLP + softmax via bf16 MFMA ----------------
// Block: 256 thr = 4 waves (2M x 2N), 32 tokens. W1T[e][h][d], W2T[e][o][h] bf16 from L2.
__global__ __launch_bounds__(256, 3) void expert_mfma_kernel(
    const float* __restrict__ x,
    const ushort* __restrict__ W1T, const float* __restrict__ b1,
    const ushort* __restrict__ W2T, const float* __restrict__ b2,
    const int* __restrict__ slot_token, const int* __restrict__ totals,
    float* __restrict__ out)
{
    __shared__ ushort xs_u[32 * 512];    // 32 KB, XOR-swizzled rows (1024 B stride)
    __shared__ ushort hb_u[32 * 128];    // 8 KB,  XOR-swizzled rows (256 B stride)
    __shared__ int    toks[32];
    __shared__ float  redm[2][32];
    __shared__ float  reds[2][32];

    const int tid  = threadIdx.x;
    const int e    = blockIdx.x >> 8;       // 256 blocks/expert
    const int sb   = blockIdx.x & 255;
    const int slot0 = sb * 32;
    int vc = totals[e]; if (vc > CAPE) vc = CAPE;
    if (slot0 >= vc) return;
    int nt = vc - slot0; if (nt > 32) nt = 32;

    const int lane = tid & 63;
    const int wid  = tid >> 6;
    const int wm   = wid & 1;              // M-group (16 rows)
    const int wn   = wid >> 1;             // N-group

    if (tid < 32) toks[tid] = (tid < nt) ? slot_token[e * CAPE + slot0 + tid] : -1;
    __syncthreads();

    char* xsb = (char*)xs_u;
    char* hbb = (char*)hb_u;

    // ---- stage x rows: f32 global -> bf16 swizzled LDS ----
    #pragma unroll
    for (int it = 0; it < 8; ++it) {
        int g = it * 256 + tid;            // 8-float group index
        int row = g >> 6, cg = g & 63;     // row 0..31, col-group of 8
        int tk = toks[row];
        float f[8];
        if (tk >= 0) {
            const float4* xp = reinterpret_cast<const float4*>(&x[(size_t)tk * D_IN + cg * 8]);
            float4 v0 = xp[0], v1 = xp[1];
            f[0]=v0.x; f[1]=v0.y; f[2]=v0.z; f[3]=v0.w;
            f[4]=v1.x; f[5]=v1.y; f[6]=v1.z; f[7]=v1.w;
        } else {
            #pragma unroll
            for (int q = 0; q < 8; ++q) f[q] = 0.f;
        }
        union { bf16x8 v; ushort u[8]; } w;
        #pragma unroll
        for (int q = 0; q < 8; ++q) w.u[q] = f2bf(f[q]);
        *reinterpret_cast<bf16x8*>(xsb + row * 1024 + ((cg * 16) ^ ((row & 7) << 4))) = w.v;
    }
    __syncthreads();

    // ---- phase 1: h = relu(x @ W1 + b1), wave = 16 rows x 64 cols ----
    {
        const int arow = wm * 16 + (lane & 15);
        const int aswz = (arow & 7) << 4;
        const int klo  = lane >> 4;
        const ushort* w1base = W1T + ((size_t)e * H_DIM + wn * 64 + (lane & 15)) * D_IN + klo * 8;

        f32x4 acc1[4] = {};
        #pragma unroll 4
        for (int kt = 0; kt < 512; kt += 32) {
            bf16x8 a = *reinterpret_cast<const bf16x8*>(xsb + arow * 1024 + ((kt * 2 + klo * 16) ^ aswz));
            bf16x8 b0 = *reinterpret_cast<const bf16x8*>(w1base + 0 * 16 * D_IN + kt);
            bf16x8 b1f = *reinterpret_cast<const bf16x8*>(w1base + 1 * 16 * D_IN + kt);
            bf16x8 b2f = *reinterpret_cast<const bf16x8*>(w1base + 2 * 16 * D_IN + kt);
            bf16x8 b3f = *reinterpret_cast<const bf16x8*>(w1base + 3 * 16 * D_IN + kt);
            acc1[0] = __builtin_amdgcn_mfma_f32_16x16x32_bf16(a, b0, acc1[0], 0, 0, 0);
            acc1[1] = __builtin_amdgcn_mfma_f32_16x16x32_bf16(a, b1f, acc1[1], 0, 0, 0);
            acc1[2] = __builtin_amdgcn_mfma_f32_16x16x32_bf16(a, b2f, acc1[2], 0, 0, 0);
            acc1[3] = __builtin_amdgcn_mfma_f32_16x16x32_bf16(a, b3f, acc1[3], 0, 0, 0);
        }
        // epilogue: bias + relu -> bf16 swizzled LDS
        #pragma unroll
        for (int f = 0; f < 4; ++f) {
            int col = wn * 64 + f * 16 + (lane & 15);
            float bv = b1[e * H_DIM + col];
            #pragma unroll
            for (int j = 0; j < 4; ++j) {
                int row = wm * 16 + (lane >> 4) * 4 + j;
                float v = acc1[f][j] + bv;
                v = v > 0.f ? v : 0.f;
                *reinterpret_cast<ushort*>(hbb + row * 256 + ((col * 2) ^ ((row & 7) << 4))) = f2bf(v);
            }
        }
    }
    __syncthreads();

    // ---- phase 2: logits = h @ W2 + b2, wave = 16 rows x 256 cols, then softmax ----
    {
        const int m0 = wm * 16;
        const int n0 = wn * 256;
        const int hrow = m0 + (lane & 15);
        const int hswz = (hrow & 7) << 4;
        const int klo  = lane >> 4;
        const ushort* w2base = W2T + ((size_t)e * O_DIM + n0 + (lane & 15)) * H_DIM + klo * 8;

        f32x4 acc2[16] = {};
        #pragma unroll
        for (int kt = 0; kt < 128; kt += 32) {
            bf16x8 a = *reinterpret_cast<const bf16x8*>(hbb + hrow * 256 + ((kt * 2 + klo * 16) ^ hswz));
            #pragma unroll
            for (int f = 0; f < 16; ++f) {
                bf16x8 b = *reinterpret_cast<const bf16x8*>(w2base + f * 16 * H_DIM + kt);
                acc2[f] = __builtin_amdgcn_mfma_f32_16x16x32_bf16(a, b, acc2[f], 0, 0, 0);
            }
        }
        // + bias
        #pragma unroll
        for (int f = 0; f < 16; ++f) {
            float bv = b2[e * O_DIM + n0 + f * 16 + (lane & 15)];
            #pragma unroll
            for (int j = 0; j < 4; ++j) acc2[f][j] += bv;
        }
        // partial row-max (over this wave's 256 cols)
        float Mj[4];
        #pragma unroll
        for (int j = 0; j < 4; ++j) {
            float m = acc2[0][j];
            #pragma unroll
            for (int f = 1; f < 16; ++f) m = fmaxf(m, acc2[f][j]);
            #pragma unroll
            for (int msk = 1; msk < 16; msk <<= 1) m = fmaxf(m, __shfl_xor(m, msk, 64));
            Mj[j] = m;
        }
        if ((lane & 15) == 0) {
            #pragma unroll
            for (int j = 0; j < 4; ++j) redm[wn][m0 + (lane >> 4) * 4 + j] = Mj[j];
        }
        __syncthreads();
        // exp + partial sums
        float Sj[4];
        #pragma unroll
        for (int j = 0; j < 4; ++j) {
            int row = m0 + (lane >> 4) * 4 + j;
            float Mg = fmaxf(redm[0][row], redm[1][row]);
            float s = 0.f;
            #pragma unroll
            for (int f = 0; f < 16; ++f) {
                float ex = expf(acc2[f][j] - Mg);
                acc2[f][j] = ex;
                s += ex;
            }
            #pragma unroll
            for (int msk = 1; msk < 16; msk <<= 1) s += __shfl_xor(s, msk, 64);
            Sj[j] = s;
        }
        if ((lane & 15) == 0) {
            #pragma unroll
            for (int j = 0; j < 4; ++j) reds[wn][m0 + (lane >> 4) * 4 + j] = Sj[j];
        }
        __syncthreads();
        // normalize + scatter to out[token]
        #pragma unroll
        for (int j = 0; j < 4; ++j) {
            int row = m0 + (lane >> 4) * 4 + j;
            int tk = toks[row];
            if (tk < 0) continue;
            float inv = 1.f / (reds[0][row] + reds[1][row]);
            float* orow = out + (size_t)tk * O_DIM + n0 + (lane & 15);
            #pragma unroll
            for (int f = 0; f < 16; ++f) orow[f * 16] = acc2[f][j] * inv;
        }
    }
}

// ---------------- K5: zero rows of dropped tokens ----------------
__global__ __launch_bounds__(256) void zero_dropped_kernel(const int* __restrict__ dropCount,
        const int* __restrict__ dropList, float* __restrict__ out)
{
    int cnt = *dropCount;
    for (int i = blockIdx.x; i < cnt; i += gridDim.x) {
        int n = dropList[i];
        reinterpret_cast<float2*>(&out[(size_t)n * O_DIM])[threadIdx.x] = make_float2(0.f, 0.f);
    }
}

extern "C" void kernel_launch(void* const* d_in, const int* in_sizes, int n_in,
                              void* d_out, int out_size, void* d_ws, size_t ws_size,
                              hipStream_t stream) {
    (void)in_sizes; (void)n_in; (void)out_size; (void)ws_size;
    const float* x   = (const float*)d_in[0];
    const float* Wg1 = (const float*)d_in[1];
    const float* bg1 = (const float*)d_in[2];
    const float* Wg2 = (const float*)d_in[3];
    const float* bg2 = (const float*)d_in[4];
    const float* W1  = (const float*)d_in[5];
    const float* b1  = (const float*)d_in[6];
    const float* W2  = (const float*)d_in[7];
    const float* b2  = (const float*)d_in[8];
    float* out = (float*)d_out;

    char* ws = (char*)d_ws;
    size_t off = 0;
    int* dropCount   = (int*)(ws + off); off += 256;
    int* top_expert  = (int*)(ws + off); off += (size_t)N_TOK * 4;          // 512 KB
    int* blockCounts = (int*)(ws + off); off += 256 * 16 * 4;               // 16 KB
    int* blockOffs   = (int*)(ws + off); off += 256 * 16 * 4;               // 16 KB
    int* totals      = (int*)(ws + off); off += 256;
    int* slot_token  = (int*)(ws + off); off += (size_t)E_EXP * CAPE * 4;   // 512 KB
    int* dropList    = (int*)(ws + off); off += (size_t)N_TOK * 4;          // 512 KB
    ushort* W1T      = (ushort*)(ws + off); off += (size_t)E_EXP * D_IN * H_DIM * 2;  // 2 MB
    ushort* W2T      = (ushort*)(ws + off); off += (size_t)E_EXP * H_DIM * O_DIM * 2; // 2 MB

    hipMemsetAsync(dropCount, 0, 4, stream);
    cvt_transpose_kernel<D_IN, H_DIM><<<E_EXP * (D_IN/32) * (H_DIM/32), 256, 0, stream>>>(W1, W1T);
    cvt_transpose_kernel<H_DIM, O_DIM><<<E_EXP * (H_DIM/32) * (O_DIM/32), 256, 0, stream>>>(W2, W2T);
    gating_kernel<<<N_TOK / 64, 256, 0, stream>>>(x, Wg1, bg1, Wg2, bg2, top_expert);
    count_kernel<<<N_TOK / 512, 256, 0, stream>>>(top_expert, blockCounts);
    scan_kernel<<<1, 64, 0, stream>>>(blockCounts, blockOffs, totals);
    scatter_kernel<<<N_TOK / 512, 64, 0, stream>>>(top_expert, blockOffs, slot_token, dropCount, dropList);
    expert_mfma_kernel<<<E_EXP * (CAPE / 32), 256, 0, stream>>>(x, W1T, b1, W2T, b2, slot_token, totals, out);
    zero_dropped_kernel<<<256, 256, 0, stream>>>(dropCount, dropList, out);
}